// Round 8
// baseline (325.068 us; speedup 1.0000x reference)
//
#include <hip/hip_runtime.h>
#include <hip/hip_bf16.h>
#include <math.h>

#define B_  256
#define N_  80
#define C_  1024
#define CO_ 1024

typedef __hip_bfloat16 bf16;
using bf16x8 = __attribute__((ext_vector_type(8))) short;   // 8 bf16 = 4 VGPRs
using f32x4  = __attribute__((ext_vector_type(4))) float;

__device__ __forceinline__ float leaky(float v){ return v >= 0.f ? v : 0.2f * v; }
__device__ __forceinline__ float sigmoidf_(float v){ return 1.f / (1.f + __expf(-v)); }

__device__ __forceinline__ void gll16(const void* g, void* l){
    __builtin_amdgcn_global_load_lds(
        (const __attribute__((address_space(1))) void*)g,
        (__attribute__((address_space(3))) void*)l, 16, 0, 0);
}

// ---------------- K0: transpose+convert both weights: WT[n][k]=bf16(W[k][n]) --
__global__ __launch_bounds__(256) void k_convT2(const float* __restrict__ W0, const float* __restrict__ W1,
                                                bf16* __restrict__ T0, bf16* __restrict__ T1){
    __shared__ float t[32][33];
    const float* W = blockIdx.z ? W1 : W0;
    bf16* WT = blockIdx.z ? T1 : T0;
    int k0 = blockIdx.y * 32, n0 = blockIdx.x * 32;
    int tx = threadIdx.x & 31, ty = threadIdx.x >> 5;
    for (int i = ty; i < 32; i += 8) t[i][tx] = W[(size_t)(k0 + i) * 1024 + n0 + tx];
    __syncthreads();
    for (int i = ty; i < 32; i += 8)
        WT[(size_t)(n0 + i) * 1024 + k0 + tx] = __float2bfloat16(t[tx][i]);
}

// ---------------- K0b: plain casts ----------------
__global__ void k_cvt_ccw(const float* __restrict__ ccw, bf16* __restrict__ ccwb){
    int i = blockIdx.x * 256 + threadIdx.x;
    ccwb[i] = __float2bfloat16(ccw[i]);
}
__global__ void k_cvt4(const float* __restrict__ src, bf16* __restrict__ dst){
    int i = (blockIdx.x * 256 + threadIdx.x) * 4;
    float4 v = *(const float4*)(src + i);
    dst[i + 0] = __float2bfloat16(v.x);
    dst[i + 1] = __float2bfloat16(v.y);
    dst[i + 2] = __float2bfloat16(v.z);
    dst[i + 3] = __float2bfloat16(v.w);
}

// ---------------- K1: adj_s (bf16, [80][88] padded rows) ----------------
__global__ void k_adj(const float* __restrict__ A, bf16* __restrict__ adjb){
    __shared__ float d[N_];
    int t = threadIdx.x;
    if (t < N_){
        float s = 0.f;
        for (int j = 0; j < N_; j++) s += A[t * N_ + j];
        d[t] = rsqrtf(s);
    }
    __syncthreads();
    for (int idx = t; idx < N_ * N_; idx += 256){
        int i = idx / N_, j = idx - i * N_;
        adjb[i * 88 + j] = __float2bfloat16(d[i] * A[j * N_ + i] * d[j]);
    }
}

// ---------------- K2/K12: h = bf16(leaky(A[80x80] @ X[80x1024])) via MFMA ----
// MODE 0: X = x (fp32), A = static adj.  MODE 1: X = X2b (bf16), A = ADJD[b].
template<int MODE>
__global__ __launch_bounds__(256) void k_prop_mfma(const void* __restrict__ srcv,
                                                   const bf16* __restrict__ Ag_,
                                                   bf16* __restrict__ H){
    __shared__ bf16 Btl[256 * 88];
    __shared__ bf16 Al [80 * 88];
    int b = blockIdx.x, c0 = blockIdx.y * 256, tid = threadIdx.x;
    int wave = tid >> 6, lane = tid & 63;
    int l15 = lane & 15, hi = lane >> 4;

    const bf16* Ag = Ag_ + (MODE ? (size_t)b * 80 * 88 : 0);
    #pragma unroll
    for (int k = 0; k < 4; k++){
        int cb = wave * 64 + 256 * k;
        if (cb + lane < 880)
            gll16(Ag + (size_t)(cb + lane) * 8, Al + (size_t)cb * 8);
    }
    // column-per-thread transpose staging (coalesced global reads)
    {
        size_t rowbase = (size_t)b * 81920 + c0 + tid;
        #pragma unroll 8
        for (int m = 0; m < 80; m++){
            bf16 h;
            if (MODE == 0) h = __float2bfloat16(((const float*)srcv)[rowbase + (size_t)m * 1024]);
            else           h = ((const bf16*)srcv)[rowbase + (size_t)m * 1024];
            Btl[tid * 88 + m] = h;
        }
    }
    __syncthreads();

    f32x4 acc[5][4];
    #pragma unroll
    for (int i = 0; i < 5; i++)
        #pragma unroll
        for (int j = 0; j < 4; j++) acc[i][j] = (f32x4){0.f, 0.f, 0.f, 0.f};

    #pragma unroll
    for (int ks = 0; ks < 3; ks++){
        bf16x8 a[5], bv[4];
        if (ks < 2){
            int k0 = ks * 32;
            #pragma unroll
            for (int i = 0; i < 5; i++)
                a[i] = *(const bf16x8*)(Al + (i * 16 + l15) * 88 + k0 + hi * 8);
            #pragma unroll
            for (int j = 0; j < 4; j++)
                bv[j] = *(const bf16x8*)(Btl + (wave * 64 + j * 16 + l15) * 88 + k0 + hi * 8);
        } else {
            int koff = (hi < 2) ? 64 + hi * 8 : 0;
            #pragma unroll
            for (int i = 0; i < 5; i++){
                bf16x8 v = *(const bf16x8*)(Al + (i * 16 + l15) * 88 + koff);
                if (hi >= 2) v = 0;
                a[i] = v;
            }
            #pragma unroll
            for (int j = 0; j < 4; j++){
                bf16x8 v = *(const bf16x8*)(Btl + (wave * 64 + j * 16 + l15) * 88 + koff);
                if (hi >= 2) v = 0;
                bv[j] = v;
            }
        }
        #pragma unroll
        for (int i = 0; i < 5; i++)
            #pragma unroll
            for (int j = 0; j < 4; j++)
                acc[i][j] = __builtin_amdgcn_mfma_f32_16x16x32_bf16(a[i], bv[j], acc[i][j], 0, 0, 0);
    }

    #pragma unroll
    for (int i = 0; i < 5; i++){
        #pragma unroll
        for (int r = 0; r < 4; r++){
            int orow = i * 16 + hi * 4 + r;
            #pragma unroll
            for (int j = 0; j < 4; j++){
                int ocol = c0 + wave * 64 + j * 16 + l15;
                H[(size_t)b * 81920 + (size_t)orow * 1024 + ocol] =
                    __float2bfloat16(leaky(acc[i][j][r]));
            }
        }
    }
}

// ---------------- K3/K13: bf16 MFMA GEMM, A-direct-reg + B-LDS 4-buf ---------
// A rows are wave-private -> load A frags straight global->VGPR with 1-step
// register double-buffer. B staged via swizzled gll16, 4 buffers, depth-3,
// counted vmcnt(6). 128x128 tile, BK=32. Grid 1280 = 8 XCD x (20 row x 8 col).
template<int EPI>
__global__ __launch_bounds__(256) void k_gemm_mfma(const bf16* __restrict__ Abf,
                                                   const bf16* __restrict__ WT,
                                                   const float* __restrict__ Res,
                                                   void* __restrict__ Outv){
    __shared__ alignas(16) bf16 Bs[4][128 * 32];
    const int K = 1024;
    const int NT = 32;
    int tid = threadIdx.x;
    int wave = tid >> 6, lane = tid & 63;
    int l15 = lane & 15, hi = lane >> 4;

    int bid = blockIdx.x;
    int xcd = bid & 7, idx = bid >> 3;
    int row0 = (xcd * 20 + (idx >> 3)) * 128;
    int col0 = (idx & 7) * 128;

    // B staging source (pre-swizzled): thread t -> row sr, k-chunk sq
    int sr = tid >> 2;
    int sq = (tid & 3) ^ ((tid >> 3) & 3);
    const bf16* gB = WT + (size_t)(col0 + sr) * K + sq * 8;

    int wr = (wave >> 1) * 64, wc = (wave & 1) * 64;
    int soff = (hi ^ ((l15 >> 1) & 3)) * 8;      // swizzled B read slot

    // A direct: lane's frag base (row = row0+wr+l15, k = hi*8)
    const bf16* gA = Abf + (size_t)(row0 + wr + l15) * K + hi * 8;

    f32x4 acc[4][4];
    #pragma unroll
    for (int i = 0; i < 4; i++)
        #pragma unroll
        for (int j = 0; j < 4; j++) acc[i][j] = (f32x4){0.f, 0.f, 0.f, 0.f};

    auto STAGE_B = [&](int t){
        bf16* db = &Bs[t & 3][wave * 512];
        gll16(gB + t * 32, db);
        gll16(gB + (size_t)64 * K + t * 32, db + 2048);
    };

    bf16x8 a0[4], a1[4];
    STAGE_B(0); STAGE_B(1); STAGE_B(2);
    #pragma unroll
    for (int i = 0; i < 4; i++)
        a0[i] = *(const bf16x8*)(gA + (size_t)i * 16 * K);

    auto kstep = [&](int t, bf16x8 (&cur)[4], bf16x8 (&nxt)[4]){
        __builtin_amdgcn_s_barrier();
        if (t + 3 < NT) STAGE_B(t + 3);
        if (t + 1 < NT){
            #pragma unroll
            for (int i = 0; i < 4; i++)
                nxt[i] = *(const bf16x8*)(gA + (size_t)i * 16 * K + (t + 1) * 32);
        }
        if (t < NT - 3)      asm volatile("s_waitcnt vmcnt(6)" ::: "memory");
        else if (t < NT - 1) asm volatile("s_waitcnt vmcnt(4)" ::: "memory");
        else                 asm volatile("s_waitcnt vmcnt(0)" ::: "memory");
        const bf16* pb = &Bs[t & 3][0] + (wc + l15) * 32 + soff;
        bf16x8 b[4];
        #pragma unroll
        for (int j = 0; j < 4; j++) b[j] = *(const bf16x8*)(pb + j * 512);
        __builtin_amdgcn_s_setprio(1);
        #pragma unroll
        for (int i = 0; i < 4; i++)
            #pragma unroll
            for (int j = 0; j < 4; j++)
                acc[i][j] = __builtin_amdgcn_mfma_f32_16x16x32_bf16(cur[i], b[j], acc[i][j], 0, 0, 0);
        __builtin_amdgcn_s_setprio(0);
    };

    for (int t0 = 0; t0 < NT; t0 += 2){
        kstep(t0,     a0, a1);
        kstep(t0 + 1, a1, a0);
    }

    int orow = row0 + wr + hi * 4;
    int ocol = col0 + wc + l15;
    #pragma unroll
    for (int i = 0; i < 4; i++){
        #pragma unroll
        for (int r = 0; r < 4; r++){
            int rr = orow + i * 16 + r;
            #pragma unroll
            for (int j = 0; j < 4; j++){
                size_t o = (size_t)rr * 1024 + ocol + j * 16;
                float v = acc[i][j][r];
                if (EPI == 0) ((bf16*)Outv)[o] = __float2bfloat16(v + Res[o]);
                else          ((float*)Outv)[o] = leaky(v);
            }
        }
    }
}

// ---------------- K5: GLB1[b][co] = GLB0b @ cgw^T + cgb, bf16 MFMA -----------
__global__ __launch_bounds__(256) void k_gemm_glb(const bf16* __restrict__ Abf,
                                                  const bf16* __restrict__ Bw,
                                                  const float* __restrict__ bias,
                                                  float* __restrict__ Out){
    __shared__ alignas(16) bf16 As[3][128 * 32];
    __shared__ alignas(16) bf16 Bs[3][128 * 32];
    const int K = 1024;
    const int NT = 32;
    int tid = threadIdx.x;
    int wave = tid >> 6, lane = tid & 63;
    int l15 = lane & 15, hi = lane >> 4;

    int row0 = (blockIdx.x >> 3) * 128;
    int col0 = (blockIdx.x & 7) * 128;

    int sr = tid >> 2;
    int sq = (tid & 3) ^ ((tid >> 3) & 3);
    const bf16* gA = Abf + (size_t)(row0 + sr) * K + sq * 8;
    const bf16* gB = Bw  + (size_t)(col0 + sr) * K + sq * 8;

    int wr = (wave >> 1) * 64, wc = (wave & 1) * 64;
    int soff = (hi ^ ((l15 >> 1) & 3)) * 8;

    f32x4 acc[4][4];
    #pragma unroll
    for (int i = 0; i < 4; i++)
        #pragma unroll
        for (int j = 0; j < 4; j++) acc[i][j] = (f32x4){0.f, 0.f, 0.f, 0.f};

    auto STAGE = [&](int t){
        int buf = t % 3;
        int k0 = t * 32;
        bf16* da = &As[buf][wave * 512];
        bf16* db = &Bs[buf][wave * 512];
        gll16(gA + k0, da);
        gll16(gA + (size_t)64 * K + k0, da + 2048);
        gll16(gB + k0, db);
        gll16(gB + (size_t)64 * K + k0, db + 2048);
    };

    STAGE(0);
    STAGE(1);
    for (int t = 0; t < NT; ++t){
        if (t == NT - 1) asm volatile("s_waitcnt vmcnt(0)" ::: "memory");
        else             asm volatile("s_waitcnt vmcnt(4)" ::: "memory");
        __builtin_amdgcn_s_barrier();
        if (t + 2 < NT) STAGE(t + 2);
        int buf = t % 3;
        const bf16* pa = &As[buf][0] + (wr + l15) * 32 + soff;
        const bf16* pb = &Bs[buf][0] + (wc + l15) * 32 + soff;
        bf16x8 a[4], b[4];
        #pragma unroll
        for (int i = 0; i < 4; i++) a[i] = *(const bf16x8*)(pa + i * 512);
        #pragma unroll
        for (int j = 0; j < 4; j++) b[j] = *(const bf16x8*)(pb + j * 512);
        #pragma unroll
        for (int i = 0; i < 4; i++)
            #pragma unroll
            for (int j = 0; j < 4; j++)
                acc[i][j] = __builtin_amdgcn_mfma_f32_16x16x32_bf16(a[i], b[j], acc[i][j], 0, 0, 0);
    }

    int orow = row0 + wr + hi * 4;
    int ocol = col0 + wc + l15;
    #pragma unroll
    for (int i = 0; i < 4; i++){
        #pragma unroll
        for (int r = 0; r < 4; r++){
            int rr = orow + i * 16 + r;
            #pragma unroll
            for (int j = 0; j < 4; j++){
                int cl = ocol + j * 16;
                Out[(size_t)rr * 1024 + cl] = acc[i][j][r] + bias[cl];
            }
        }
    }
}

// ---------------- K4: glb0b[b,c] = bf16(mean_n x2b[b,n,c]), vectorized -------
__global__ __launch_bounds__(128) void k_pool(const bf16* __restrict__ X2b, bf16* __restrict__ glb0b){
    int b = blockIdx.x, c8 = threadIdx.x * 8;
    const bf16* p = X2b + (size_t)b * 81920 + c8;
    float s[8] = {0.f,0.f,0.f,0.f,0.f,0.f,0.f,0.f};
    for (int nn = 0; nn < N_; nn++){
        union { bf16x8 v; bf16 e[8]; } u;
        u.v = *(const bf16x8*)(p + (size_t)nn * 1024);
        #pragma unroll
        for (int k = 0; k < 8; k++) s[k] += __bfloat162float(u.e[k]);
    }
    #pragma unroll
    for (int k = 0; k < 8; k++)
        glb0b[b * C_ + c8 + k] = __float2bfloat16(s[k] * (1.f / N_));
}

// ---------------- K6: BN stats over batch (high-TLP) ----------------
__global__ __launch_bounds__(256) void k_bnstat(const float* __restrict__ g, float* __restrict__ mu,
                                                float* __restrict__ rstd){
    __shared__ float rs[8][32], rs2[8][32];
    int tid = threadIdx.x;
    int c = blockIdx.x * 32 + (tid & 31);
    int grp = tid >> 5;
    float s = 0.f, s2 = 0.f;
    for (int bb = 0; bb < 32; bb++){
        float v = g[(size_t)(grp * 32 + bb) * 1024 + c];
        s += v; s2 += v * v;
    }
    rs[grp][tid & 31] = s;
    rs2[grp][tid & 31] = s2;
    __syncthreads();
    if (tid < 32){
        float S = 0.f, S2 = 0.f;
        #pragma unroll
        for (int q = 0; q < 8; q++){ S += rs[q][tid]; S2 += rs2[q][tid]; }
        float m = S * (1.f / B_);
        float var = S2 * (1.f / B_) - m * m;
        int cc = blockIdx.x * 32 + tid;
        mu[cc] = m;
        rstd[cc] = rsqrtf(var + 1e-5f);
    }
}

// ---------------- K7: glb2b = bf16(leaky(BN(glb1))) ----------------
__global__ void k_bnapply(const float* __restrict__ g, const float* __restrict__ mu,
                          const float* __restrict__ rstd, const float* __restrict__ gamma,
                          const float* __restrict__ beta, bf16* __restrict__ o){
    int i = blockIdx.x * 256 + threadIdx.x;
    int c = i & (C_ - 1);
    float v = (g[i] - mu[c]) * rstd[c] * gamma[c] + beta[c];
    o[i] = __float2bfloat16(leaky(v));
}

// ---------------- K9: fused dyn + loss + ADJD, operand-LDS-free --------------
__global__ __launch_bounds__(320) void k_dyn_fused(const bf16* __restrict__ X2b,
                                                   const bf16* __restrict__ ccwb,
                                                   const bf16* __restrict__ glb2b,
                                                   const float* __restrict__ ccb,
                                                   const float* __restrict__ out1,
                                                   bf16* __restrict__ ADJD,
                                                   float* __restrict__ lossp){
    __shared__ float S[80][81];
    __shared__ float di_s[80], o1s[80], dd[80];
    int b = blockIdx.x, tid = threadIdx.x;
    int wave = tid >> 6, lane = tid & 63;
    int l15 = lane & 15, hi = lane >> 4;

    const bf16* arow = ccwb + (size_t)(wave * 16 + l15) * 2048 + hi * 8;
    const bf16* gG = glb2b + (size_t)b * 1024 + hi * 8;
    const bf16* gX = X2b + (size_t)b * 81920 + hi * 8;

    f32x4 acc[5];
    #pragma unroll
    for (int j = 0; j < 5; j++) acc[j] = (f32x4){0.f, 0.f, 0.f, 0.f};

    #pragma unroll 8
    for (int k0 = 0; k0 < 1024; k0 += 32){
        bf16x8 a = *(const bf16x8*)(arow + k0);
        bf16x8 g = *(const bf16x8*)(gG + k0);
        #pragma unroll
        for (int j = 0; j < 5; j++)
            acc[j] = __builtin_amdgcn_mfma_f32_16x16x32_bf16(a, g, acc[j], 0, 0, 0);
    }
    #pragma unroll 4
    for (int k0 = 0; k0 < 1024; k0 += 32){
        bf16x8 a = *(const bf16x8*)(arow + 1024 + k0);
        #pragma unroll
        for (int j = 0; j < 5; j++){
            bf16x8 bv = *(const bf16x8*)(gX + (size_t)(j * 16 + l15) * 1024 + k0);
            acc[j] = __builtin_amdgcn_mfma_f32_16x16x32_bf16(a, bv, acc[j], 0, 0, 0);
        }
    }

    #pragma unroll
    for (int r = 0; r < 4; r++){
        int n = wave * 16 + hi * 4 + r;
        float cb = ccb[n];
        #pragma unroll
        for (int j = 0; j < 5; j++)
            S[n][j * 16 + l15] = sigmoidf_(acc[j][r] + cb);
    }
    __syncthreads();
    if (tid < 80){
        float rsum = 0.f;
        for (int m = 0; m < 80; m++) rsum += S[tid][m];
        di_s[tid] = rsqrtf(rsum);
        o1s[tid] = sigmoidf_(out1[b * 80 + tid]);
    }
    __syncthreads();
    if (tid < 80){
        float cs = 0.f;
        for (int n = 0; n < 80; n++) cs += o1s[n] * S[n][tid];
        float diff = o1s[tid] - cs * (1.f / 80.f);
        dd[tid] = diff * diff;
    }
    __syncthreads();
    if (tid == 0){
        float s = 0.f;
        for (int m = 0; m < 80; m++) s += dd[m];
        lossp[b] = sqrtf(s);
    }
    bf16* ab = ADJD + (size_t)b * 80 * 88;
    for (int idx = tid; idx < 6400; idx += 320){
        int n = idx / 80, m = idx - n * 80;
        ab[n * 88 + m] = __float2bfloat16(di_s[n] * S[m][n] * di_s[m]);
    }
}

// ---------------- K11: loss = sum(lossp) ----------------
__global__ void k_lsum(const float* __restrict__ lossp, float* __restrict__ out_loss){
    float v = lossp[threadIdx.x];
    for (int off = 32; off; off >>= 1) v += __shfl_down(v, off);
    __shared__ float wsum[4];
    int lane = threadIdx.x & 63, w = threadIdx.x >> 6;
    if (lane == 0) wsum[w] = v;
    __syncthreads();
    if (threadIdx.x == 0) out_loss[0] = wsum[0] + wsum[1] + wsum[2] + wsum[3];
}

extern "C" void kernel_launch(void* const* d_in, const int* in_sizes, int n_in,
                              void* d_out, int out_size, void* d_ws, size_t ws_size,
                              hipStream_t stream) {
    const float* x     = (const float*)d_in[0];
    const float* out1  = (const float*)d_in[1];
    const float* A     = (const float*)d_in[2];
    const float* sw    = (const float*)d_in[3];
    const float* cgw   = (const float*)d_in[4];
    const float* cgb   = (const float*)d_in[5];
    const float* gamma = (const float*)d_in[6];
    const float* beta  = (const float*)d_in[7];
    const float* ccw   = (const float*)d_in[8];
    const float* ccb   = (const float*)d_in[9];
    const float* dw    = (const float*)d_in[10];
    float* out = (float*)d_out;

    const size_t XN = (size_t)B_ * N_ * C_;   // 20,971,520
    char* p = (char*)d_ws;
    bf16*  Hbf  = (bf16*)p;   p += XN * 2;               // 42 MB
    bf16*  X2b  = (bf16*)p;   p += XN * 2;               // 42 MB
    bf16*  SWT  = (bf16*)p;   p += (size_t)C_ * C_ * 2;  // 2 MB
    bf16*  DWT  = (bf16*)p;   p += (size_t)C_ * CO_ * 2; // 2 MB
    bf16*  CCWB = (bf16*)p;   p += (size_t)N_ * 2048 * 2;
    bf16*  CGWB = (bf16*)p;   p += (size_t)C_ * C_ * 2;  // 2 MB
    bf16*  ADJS = (bf16*)p;   p += (size_t)80 * 88 * 2;
    bf16*  ADJD = (bf16*)p;   p += (size_t)B_ * 80 * 88 * 2;  // 3.6 MB
    bf16*  GLB0 = (bf16*)p;   p += (size_t)B_ * C_ * 2;
    float* GLB1 = (float*)p;  p += (size_t)B_ * C_ * 4;
    bf16*  GLB2 = (bf16*)p;   p += (size_t)B_ * C_ * 2;
    float* MU   = (float*)p;  p += C_ * 4;
    float* RSTD = (float*)p;  p += C_ * 4;
    float* LOSSP= (float*)p;  p += B_ * 4;

    k_convT2<<<dim3(32, 32, 2), 256, 0, stream>>>(sw, dw, SWT, DWT);
    k_cvt_ccw<<<(N_ * 2048) / 256, 256, 0, stream>>>(ccw, CCWB);
    k_cvt4<<<(C_ * C_) / 1024, 256, 0, stream>>>(cgw, CGWB);
    k_adj<<<1, 256, 0, stream>>>(A, ADJS);
    k_prop_mfma<0><<<dim3(B_, 4), 256, 0, stream>>>(x, ADJS, Hbf);
    k_gemm_mfma<0><<<1280, 256, 0, stream>>>(Hbf, SWT, x, X2b);
    k_pool<<<B_, 128, 0, stream>>>(X2b, GLB0);
    k_gemm_glb<<<16, 256, 0, stream>>>(GLB0, CGWB, cgb, GLB1);
    k_bnstat<<<32, 256, 0, stream>>>(GLB1, MU, RSTD);
    k_bnapply<<<(B_ * C_) / 256, 256, 0, stream>>>(GLB1, MU, RSTD, gamma, beta, GLB2);
    k_dyn_fused<<<B_, 320, 0, stream>>>(X2b, CCWB, GLB2, ccb, out1, ADJD, LOSSP);
    k_lsum<<<1, 256, 0, stream>>>(LOSSP, out + (size_t)B_ * N_ * CO_);
    k_prop_mfma<1><<<dim3(B_, 4), 256, 0, stream>>>(X2b, ADJD, Hbf);
    k_gemm_mfma<1><<<1280, 256, 0, stream>>>(Hbf, DWT, nullptr, out);
}

// Round 9
// 273.051 us; speedup vs baseline: 1.1905x; 1.1905x over previous
//
#include <hip/hip_runtime.h>
#include <hip/hip_bf16.h>
#include <math.h>

#define B_  256
#define N_  80
#define C_  1024
#define CO_ 1024

typedef __hip_bfloat16 bf16;
using bf16x8 = __attribute__((ext_vector_type(8))) short;   // 8 bf16 = 4 VGPRs
using f32x4  = __attribute__((ext_vector_type(4))) float;

__device__ __forceinline__ float leaky(float v){ return v >= 0.f ? v : 0.2f * v; }
__device__ __forceinline__ float sigmoidf_(float v){ return 1.f / (1.f + __expf(-v)); }

__device__ __forceinline__ void gll16(const void* g, void* l){
    __builtin_amdgcn_global_load_lds(
        (const __attribute__((address_space(1))) void*)g,
        (__attribute__((address_space(3))) void*)l, 16, 0, 0);
}

// ---------------- K0: transpose+convert both weights: WT[n][k]=bf16(W[k][n]) --
__global__ __launch_bounds__(256) void k_convT2(const float* __restrict__ W0, const float* __restrict__ W1,
                                                bf16* __restrict__ T0, bf16* __restrict__ T1){
    __shared__ float t[32][33];
    const float* W = blockIdx.z ? W1 : W0;
    bf16* WT = blockIdx.z ? T1 : T0;
    int k0 = blockIdx.y * 32, n0 = blockIdx.x * 32;
    int tx = threadIdx.x & 31, ty = threadIdx.x >> 5;
    for (int i = ty; i < 32; i += 8) t[i][tx] = W[(size_t)(k0 + i) * 1024 + n0 + tx];
    __syncthreads();
    for (int i = ty; i < 32; i += 8)
        WT[(size_t)(n0 + i) * 1024 + k0 + tx] = __float2bfloat16(t[tx][i]);
}

// ---------------- K0b: plain casts ----------------
__global__ void k_cvt_ccw(const float* __restrict__ ccw, bf16* __restrict__ ccwb){
    int i = blockIdx.x * 256 + threadIdx.x;
    ccwb[i] = __float2bfloat16(ccw[i]);
}
__global__ void k_cvt4(const float* __restrict__ src, bf16* __restrict__ dst){
    int i = (blockIdx.x * 256 + threadIdx.x) * 4;
    float4 v = *(const float4*)(src + i);
    dst[i + 0] = __float2bfloat16(v.x);
    dst[i + 1] = __float2bfloat16(v.y);
    dst[i + 2] = __float2bfloat16(v.z);
    dst[i + 3] = __float2bfloat16(v.w);
}

// ---------------- K1: adj_s (bf16, [80][88] padded rows) ----------------
__global__ void k_adj(const float* __restrict__ A, bf16* __restrict__ adjb){
    __shared__ float d[N_];
    int t = threadIdx.x;
    if (t < N_){
        float s = 0.f;
        for (int j = 0; j < N_; j++) s += A[t * N_ + j];
        d[t] = rsqrtf(s);
    }
    __syncthreads();
    for (int idx = t; idx < N_ * N_; idx += 256){
        int i = idx / N_, j = idx - i * N_;
        adjb[i * 88 + j] = __float2bfloat16(d[i] * A[j * N_ + i] * d[j]);
    }
}

// ---------------- K2/K12: h = bf16(leaky(A[80x80] @ X[80x1024])) via MFMA ----
// 128 cols per block, 2 waves (36.6KB LDS -> 4 blocks/CU). grid (B, 8).
template<int MODE>
__global__ __launch_bounds__(128) void k_prop_mfma(const void* __restrict__ srcv,
                                                   const bf16* __restrict__ Ag_,
                                                   bf16* __restrict__ H){
    __shared__ bf16 Btl[128 * 88];
    __shared__ bf16 Al [80 * 88];
    int b = blockIdx.x, c0 = blockIdx.y * 128, tid = threadIdx.x;
    int wave = tid >> 6, lane = tid & 63;
    int l15 = lane & 15, hi = lane >> 4;

    const bf16* Ag = Ag_ + (MODE ? (size_t)b * 80 * 88 : 0);
    #pragma unroll
    for (int k = 0; k < 7; k++){
        int cb = k * 128 + wave * 64;            // wave-uniform chunk base
        if (cb + lane < 880)
            gll16(Ag + (size_t)(cb + lane) * 8, Al + (size_t)cb * 8);
    }
    // column-per-thread transpose staging (coalesced global reads)
    {
        size_t rowbase = (size_t)b * 81920 + c0 + tid;
        #pragma unroll 8
        for (int m = 0; m < 80; m++){
            bf16 h;
            if (MODE == 0) h = __float2bfloat16(((const float*)srcv)[rowbase + (size_t)m * 1024]);
            else           h = ((const bf16*)srcv)[rowbase + (size_t)m * 1024];
            Btl[tid * 88 + m] = h;
        }
    }
    __syncthreads();

    f32x4 acc[5][4];
    #pragma unroll
    for (int i = 0; i < 5; i++)
        #pragma unroll
        for (int j = 0; j < 4; j++) acc[i][j] = (f32x4){0.f, 0.f, 0.f, 0.f};

    #pragma unroll
    for (int ks = 0; ks < 3; ks++){
        bf16x8 a[5], bv[4];
        if (ks < 2){
            int k0 = ks * 32;
            #pragma unroll
            for (int i = 0; i < 5; i++)
                a[i] = *(const bf16x8*)(Al + (i * 16 + l15) * 88 + k0 + hi * 8);
            #pragma unroll
            for (int j = 0; j < 4; j++)
                bv[j] = *(const bf16x8*)(Btl + (wave * 64 + j * 16 + l15) * 88 + k0 + hi * 8);
        } else {
            int koff = (hi < 2) ? 64 + hi * 8 : 0;
            #pragma unroll
            for (int i = 0; i < 5; i++){
                bf16x8 v = *(const bf16x8*)(Al + (i * 16 + l15) * 88 + koff);
                if (hi >= 2) v = 0;
                a[i] = v;
            }
            #pragma unroll
            for (int j = 0; j < 4; j++){
                bf16x8 v = *(const bf16x8*)(Btl + (wave * 64 + j * 16 + l15) * 88 + koff);
                if (hi >= 2) v = 0;
                bv[j] = v;
            }
        }
        #pragma unroll
        for (int i = 0; i < 5; i++)
            #pragma unroll
            for (int j = 0; j < 4; j++)
                acc[i][j] = __builtin_amdgcn_mfma_f32_16x16x32_bf16(a[i], bv[j], acc[i][j], 0, 0, 0);
    }

    #pragma unroll
    for (int i = 0; i < 5; i++){
        #pragma unroll
        for (int r = 0; r < 4; r++){
            int orow = i * 16 + hi * 4 + r;
            #pragma unroll
            for (int j = 0; j < 4; j++){
                int ocol = c0 + wave * 64 + j * 16 + l15;
                H[(size_t)b * 81920 + (size_t)orow * 1024 + ocol] =
                    __float2bfloat16(leaky(acc[i][j][r]));
            }
        }
    }
}

// ---------------- K3/K13: bf16 MFMA GEMM, A 3-buf / B 2-buf (40KB -> 4/CU) ---
// r7 pipeline with asymmetric depth: A (HBM stream) depth-2, B (L2-hot) depth-1.
// Steady state: wait vmcnt(2) BEFORE barrier (drains A(t),B(t) per wave);
// after barrier issue STAGE_B(t+1), STAGE_A(t+2). 128x128 tile, BK=32.
template<int EPI>
__global__ __launch_bounds__(256, 4) void k_gemm_mfma(const bf16* __restrict__ Abf,
                                                      const bf16* __restrict__ WT,
                                                      const float* __restrict__ Res,
                                                      void* __restrict__ Outv){
    __shared__ alignas(16) bf16 As[3][128 * 32];
    __shared__ alignas(16) bf16 Bs[2][128 * 32];
    const int K = 1024;
    const int NT = 32;
    int tid = threadIdx.x;
    int wave = tid >> 6, lane = tid & 63;
    int l15 = lane & 15, hi = lane >> 4;

    int bid = blockIdx.x;
    int xcd = bid & 7, idx = bid >> 3;
    int row0 = (xcd * 20 + (idx >> 3)) * 128;
    int col0 = (idx & 7) * 128;

    int sr = tid >> 2;
    int sq = (tid & 3) ^ ((tid >> 3) & 3);
    const bf16* gA = Abf + (size_t)(row0 + sr) * K + sq * 8;
    const bf16* gB = WT  + (size_t)(col0 + sr) * K + sq * 8;

    int wr = (wave >> 1) * 64, wc = (wave & 1) * 64;
    int soff = (hi ^ ((l15 >> 1) & 3)) * 8;

    f32x4 acc[4][4];
    #pragma unroll
    for (int i = 0; i < 4; i++)
        #pragma unroll
        for (int j = 0; j < 4; j++) acc[i][j] = (f32x4){0.f, 0.f, 0.f, 0.f};

    auto STAGE_A = [&](int t){
        bf16* da = &As[t % 3][wave * 512];
        gll16(gA + t * 32, da);
        gll16(gA + (size_t)64 * K + t * 32, da + 2048);
    };
    auto STAGE_B = [&](int t){
        bf16* db = &Bs[t & 1][wave * 512];
        gll16(gB + t * 32, db);
        gll16(gB + (size_t)64 * K + t * 32, db + 2048);
    };

    STAGE_A(0); STAGE_B(0); STAGE_A(1);
    for (int t = 0; t < NT; ++t){
        if (t < NT - 1) asm volatile("s_waitcnt vmcnt(2)" ::: "memory");
        else            asm volatile("s_waitcnt vmcnt(0)" ::: "memory");
        __builtin_amdgcn_s_barrier();
        if (t + 1 < NT) STAGE_B(t + 1);
        if (t + 2 < NT) STAGE_A(t + 2);
        const bf16* pa = &As[t % 3][0] + (wr + l15) * 32 + soff;
        const bf16* pb = &Bs[t & 1][0] + (wc + l15) * 32 + soff;
        bf16x8 a[4], b[4];
        #pragma unroll
        for (int i = 0; i < 4; i++) a[i] = *(const bf16x8*)(pa + i * 512);
        #pragma unroll
        for (int j = 0; j < 4; j++) b[j] = *(const bf16x8*)(pb + j * 512);
        __builtin_amdgcn_s_setprio(1);
        #pragma unroll
        for (int i = 0; i < 4; i++)
            #pragma unroll
            for (int j = 0; j < 4; j++)
                acc[i][j] = __builtin_amdgcn_mfma_f32_16x16x32_bf16(a[i], b[j], acc[i][j], 0, 0, 0);
        __builtin_amdgcn_s_setprio(0);
    }

    int orow = row0 + wr + hi * 4;
    int ocol = col0 + wc + l15;
    #pragma unroll
    for (int i = 0; i < 4; i++){
        #pragma unroll
        for (int r = 0; r < 4; r++){
            int rr = orow + i * 16 + r;
            #pragma unroll
            for (int j = 0; j < 4; j++){
                size_t o = (size_t)rr * 1024 + ocol + j * 16;
                float v = acc[i][j][r];
                if (EPI == 0) ((bf16*)Outv)[o] = __float2bfloat16(v + Res[o]);
                else          ((float*)Outv)[o] = leaky(v);
            }
        }
    }
}

// ---------------- K5: GLB1[b][co] = GLB0b @ cgw^T + cgb, bf16 MFMA -----------
__global__ __launch_bounds__(256) void k_gemm_glb(const bf16* __restrict__ Abf,
                                                  const bf16* __restrict__ Bw,
                                                  const float* __restrict__ bias,
                                                  float* __restrict__ Out){
    __shared__ alignas(16) bf16 As[3][128 * 32];
    __shared__ alignas(16) bf16 Bs[3][128 * 32];
    const int K = 1024;
    const int NT = 32;
    int tid = threadIdx.x;
    int wave = tid >> 6, lane = tid & 63;
    int l15 = lane & 15, hi = lane >> 4;

    int row0 = (blockIdx.x >> 3) * 128;
    int col0 = (blockIdx.x & 7) * 128;

    int sr = tid >> 2;
    int sq = (tid & 3) ^ ((tid >> 3) & 3);
    const bf16* gA = Abf + (size_t)(row0 + sr) * K + sq * 8;
    const bf16* gB = Bw  + (size_t)(col0 + sr) * K + sq * 8;

    int wr = (wave >> 1) * 64, wc = (wave & 1) * 64;
    int soff = (hi ^ ((l15 >> 1) & 3)) * 8;

    f32x4 acc[4][4];
    #pragma unroll
    for (int i = 0; i < 4; i++)
        #pragma unroll
        for (int j = 0; j < 4; j++) acc[i][j] = (f32x4){0.f, 0.f, 0.f, 0.f};

    auto STAGE = [&](int t){
        int buf = t % 3;
        int k0 = t * 32;
        bf16* da = &As[buf][wave * 512];
        bf16* db = &Bs[buf][wave * 512];
        gll16(gA + k0, da);
        gll16(gA + (size_t)64 * K + k0, da + 2048);
        gll16(gB + k0, db);
        gll16(gB + (size_t)64 * K + k0, db + 2048);
    };

    STAGE(0);
    STAGE(1);
    for (int t = 0; t < NT; ++t){
        if (t == NT - 1) asm volatile("s_waitcnt vmcnt(0)" ::: "memory");
        else             asm volatile("s_waitcnt vmcnt(4)" ::: "memory");
        __builtin_amdgcn_s_barrier();
        if (t + 2 < NT) STAGE(t + 2);
        int buf = t % 3;
        const bf16* pa = &As[buf][0] + (wr + l15) * 32 + soff;
        const bf16* pb = &Bs[buf][0] + (wc + l15) * 32 + soff;
        bf16x8 a[4], b[4];
        #pragma unroll
        for (int i = 0; i < 4; i++) a[i] = *(const bf16x8*)(pa + i * 512);
        #pragma unroll
        for (int j = 0; j < 4; j++) b[j] = *(const bf16x8*)(pb + j * 512);
        #pragma unroll
        for (int i = 0; i < 4; i++)
            #pragma unroll
            for (int j = 0; j < 4; j++)
                acc[i][j] = __builtin_amdgcn_mfma_f32_16x16x32_bf16(a[i], b[j], acc[i][j], 0, 0, 0);
    }

    int orow = row0 + wr + hi * 4;
    int ocol = col0 + wc + l15;
    #pragma unroll
    for (int i = 0; i < 4; i++){
        #pragma unroll
        for (int r = 0; r < 4; r++){
            int rr = orow + i * 16 + r;
            #pragma unroll
            for (int j = 0; j < 4; j++){
                int cl = ocol + j * 16;
                Out[(size_t)rr * 1024 + cl] = acc[i][j][r] + bias[cl];
            }
        }
    }
}

// ---------------- K4: glb0b[b,c] = bf16(mean_n x2b[b,n,c]), vectorized -------
__global__ __launch_bounds__(128) void k_pool(const bf16* __restrict__ X2b, bf16* __restrict__ glb0b){
    int b = blockIdx.x, c8 = threadIdx.x * 8;
    const bf16* p = X2b + (size_t)b * 81920 + c8;
    float s[8] = {0.f,0.f,0.f,0.f,0.f,0.f,0.f,0.f};
    for (int nn = 0; nn < N_; nn++){
        union { bf16x8 v; bf16 e[8]; } u;
        u.v = *(const bf16x8*)(p + (size_t)nn * 1024);
        #pragma unroll
        for (int k = 0; k < 8; k++) s[k] += __bfloat162float(u.e[k]);
    }
    #pragma unroll
    for (int k = 0; k < 8; k++)
        glb0b[b * C_ + c8 + k] = __float2bfloat16(s[k] * (1.f / N_));
}

// ---------------- K6: BN stats over batch (high-TLP) ----------------
__global__ __launch_bounds__(256) void k_bnstat(const float* __restrict__ g, float* __restrict__ mu,
                                                float* __restrict__ rstd){
    __shared__ float rs[8][32], rs2[8][32];
    int tid = threadIdx.x;
    int c = blockIdx.x * 32 + (tid & 31);
    int grp = tid >> 5;
    float s = 0.f, s2 = 0.f;
    for (int bb = 0; bb < 32; bb++){
        float v = g[(size_t)(grp * 32 + bb) * 1024 + c];
        s += v; s2 += v * v;
    }
    rs[grp][tid & 31] = s;
    rs2[grp][tid & 31] = s2;
    __syncthreads();
    if (tid < 32){
        float S = 0.f, S2 = 0.f;
        #pragma unroll
        for (int q = 0; q < 8; q++){ S += rs[q][tid]; S2 += rs2[q][tid]; }
        float m = S * (1.f / B_);
        float var = S2 * (1.f / B_) - m * m;
        int cc = blockIdx.x * 32 + tid;
        mu[cc] = m;
        rstd[cc] = rsqrtf(var + 1e-5f);
    }
}

// ---------------- K7: glb2b = bf16(leaky(BN(glb1))) ----------------
__global__ void k_bnapply(const float* __restrict__ g, const float* __restrict__ mu,
                          const float* __restrict__ rstd, const float* __restrict__ gamma,
                          const float* __restrict__ beta, bf16* __restrict__ o){
    int i = blockIdx.x * 256 + threadIdx.x;
    int c = i & (C_ - 1);
    float v = (g[i] - mu[c]) * rstd[c] * gamma[c] + beta[c];
    o[i] = __float2bfloat16(leaky(v));
}

// ---------------- K9: fused dyn + loss + ADJD, operand-LDS-free --------------
__global__ __launch_bounds__(320) void k_dyn_fused(const bf16* __restrict__ X2b,
                                                   const bf16* __restrict__ ccwb,
                                                   const bf16* __restrict__ glb2b,
                                                   const float* __restrict__ ccb,
                                                   const float* __restrict__ out1,
                                                   bf16* __restrict__ ADJD,
                                                   float* __restrict__ lossp){
    __shared__ float S[80][81];
    __shared__ float di_s[80], o1s[80], dd[80];
    int b = blockIdx.x, tid = threadIdx.x;
    int wave = tid >> 6, lane = tid & 63;
    int l15 = lane & 15, hi = lane >> 4;

    const bf16* arow = ccwb + (size_t)(wave * 16 + l15) * 2048 + hi * 8;
    const bf16* gG = glb2b + (size_t)b * 1024 + hi * 8;
    const bf16* gX = X2b + (size_t)b * 81920 + hi * 8;

    f32x4 acc[5];
    #pragma unroll
    for (int j = 0; j < 5; j++) acc[j] = (f32x4){0.f, 0.f, 0.f, 0.f};

    #pragma unroll 8
    for (int k0 = 0; k0 < 1024; k0 += 32){
        bf16x8 a = *(const bf16x8*)(arow + k0);
        bf16x8 g = *(const bf16x8*)(gG + k0);
        #pragma unroll
        for (int j = 0; j < 5; j++)
            acc[j] = __builtin_amdgcn_mfma_f32_16x16x32_bf16(a, g, acc[j], 0, 0, 0);
    }
    #pragma unroll 4
    for (int k0 = 0; k0 < 1024; k0 += 32){
        bf16x8 a = *(const bf16x8*)(arow + 1024 + k0);
        #pragma unroll
        for (int j = 0; j < 5; j++){
            bf16x8 bv = *(const bf16x8*)(gX + (size_t)(j * 16 + l15) * 1024 + k0);
            acc[j] = __builtin_amdgcn_mfma_f32_16x16x32_bf16(a, bv, acc[j], 0, 0, 0);
        }
    }

    #pragma unroll
    for (int r = 0; r < 4; r++){
        int n = wave * 16 + hi * 4 + r;
        float cb = ccb[n];
        #pragma unroll
        for (int j = 0; j < 5; j++)
            S[n][j * 16 + l15] = sigmoidf_(acc[j][r] + cb);
    }
    __syncthreads();
    if (tid < 80){
        float rsum = 0.f;
        for (int m = 0; m < 80; m++) rsum += S[tid][m];
        di_s[tid] = rsqrtf(rsum);
        o1s[tid] = sigmoidf_(out1[b * 80 + tid]);
    }
    __syncthreads();
    if (tid < 80){
        float cs = 0.f;
        for (int n = 0; n < 80; n++) cs += o1s[n] * S[n][tid];
        float diff = o1s[tid] - cs * (1.f / 80.f);
        dd[tid] = diff * diff;
    }
    __syncthreads();
    if (tid == 0){
        float s = 0.f;
        for (int m = 0; m < 80; m++) s += dd[m];
        lossp[b] = sqrtf(s);
    }
    bf16* ab = ADJD + (size_t)b * 80 * 88;
    for (int idx = tid; idx < 6400; idx += 320){
        int n = idx / 80, m = idx - n * 80;
        ab[n * 88 + m] = __float2bfloat16(di_s[n] * S[m][n] * di_s[m]);
    }
}

// ---------------- K11: loss = sum(lossp) ----------------
__global__ void k_lsum(const float* __restrict__ lossp, float* __restrict__ out_loss){
    float v = lossp[threadIdx.x];
    for (int off = 32; off; off >>= 1) v += __shfl_down(v, off);
    __shared__ float wsum[4];
    int lane = threadIdx.x & 63, w = threadIdx.x >> 6;
    if (lane == 0) wsum[w] = v;
    __syncthreads();
    if (threadIdx.x == 0) out_loss[0] = wsum[0] + wsum[1] + wsum[2] + wsum[3];
}

extern "C" void kernel_launch(void* const* d_in, const int* in_sizes, int n_in,
                              void* d_out, int out_size, void* d_ws, size_t ws_size,
                              hipStream_t stream) {
    const float* x     = (const float*)d_in[0];
    const float* out1  = (const float*)d_in[1];
    const float* A     = (const float*)d_in[2];
    const float* sw    = (const float*)d_in[3];
    const float* cgw   = (const float*)d_in[4];
    const float* cgb   = (const float*)d_in[5];
    const float* gamma = (const float*)d_in[6];
    const float* beta  = (const float*)d_in[7];
    const float* ccw   = (const float*)d_in[8];
    const float* ccb   = (const float*)d_in[9];
    const float* dw    = (const float*)d_in[10];
    float* out = (float*)d_out;

    const size_t XN = (size_t)B_ * N_ * C_;   // 20,971,520
    char* p = (char*)d_ws;
    bf16*  Hbf  = (bf16*)p;   p += XN * 2;               // 42 MB
    bf16*  X2b  = (bf16*)p;   p += XN * 2;               // 42 MB
    bf16*  SWT  = (bf16*)p;   p += (size_t)C_ * C_ * 2;  // 2 MB
    bf16*  DWT  = (bf16*)p;   p += (size_t)C_ * CO_ * 2; // 2 MB
    bf16*  CCWB = (bf16*)p;   p += (size_t)N_ * 2048 * 2;
    bf16*  CGWB = (bf16*)p;   p += (size_t)C_ * C_ * 2;  // 2 MB
    bf16*  ADJS = (bf16*)p;   p += (size_t)80 * 88 * 2;
    bf16*  ADJD = (bf16*)p;   p += (size_t)B_ * 80 * 88 * 2;  // 3.6 MB
    bf16*  GLB0 = (bf16*)p;   p += (size_t)B_ * C_ * 2;
    float* GLB1 = (float*)p;  p += (size_t)B_ * C_ * 4;
    bf16*  GLB2 = (bf16*)p;   p += (size_t)B_ * C_ * 2;
    float* MU   = (float*)p;  p += C_ * 4;
    float* RSTD = (float*)p;  p += C_ * 4;
    float* LOSSP= (float*)p;  p += B_ * 4;

    k_convT2<<<dim3(32, 32, 2), 256, 0, stream>>>(sw, dw, SWT, DWT);
    k_cvt_ccw<<<(N_ * 2048) / 256, 256, 0, stream>>>(ccw, CCWB);
    k_cvt4<<<(C_ * C_) / 1024, 256, 0, stream>>>(cgw, CGWB);
    k_adj<<<1, 256, 0, stream>>>(A, ADJS);
    k_prop_mfma<0><<<dim3(B_, 8), 128, 0, stream>>>(x, ADJS, Hbf);
    k_gemm_mfma<0><<<1280, 256, 0, stream>>>(Hbf, SWT, x, X2b);
    k_pool<<<B_, 128, 0, stream>>>(X2b, GLB0);
    k_gemm_glb<<<16, 256, 0, stream>>>(GLB0, CGWB, cgb, GLB1);
    k_bnstat<<<32, 256, 0, stream>>>(GLB1, MU, RSTD);
    k_bnapply<<<(B_ * C_) / 256, 256, 0, stream>>>(GLB1, MU, RSTD, gamma, beta, GLB2);
    k_dyn_fused<<<B_, 320, 0, stream>>>(X2b, CCWB, GLB2, ccb, out1, ADJD, LOSSP);
    k_lsum<<<1, 256, 0, stream>>>(LOSSP, out + (size_t)B_ * N_ * CO_);
    k_prop_mfma<1><<<dim3(B_, 8), 128, 0, stream>>>(X2b, ADJD, Hbf);
    k_gemm_mfma<1><<<1280, 256, 0, stream>>>(Hbf, DWT, nullptr, out);
}

// Round 10
// 271.854 us; speedup vs baseline: 1.1957x; 1.0044x over previous
//
#include <hip/hip_runtime.h>
#include <hip/hip_bf16.h>
#include <math.h>

#define B_  256
#define N_  80
#define C_  1024
#define CO_ 1024

typedef __hip_bfloat16 bf16;
using bf16x8 = __attribute__((ext_vector_type(8))) short;   // 8 bf16 = 4 VGPRs
using f32x4  = __attribute__((ext_vector_type(4))) float;

__device__ __forceinline__ float leaky(float v){ return v >= 0.f ? v : 0.2f * v; }
__device__ __forceinline__ float sigmoidf_(float v){ return 1.f / (1.f + __expf(-v)); }

__device__ __forceinline__ void gll16(const void* g, void* l){
    __builtin_amdgcn_global_load_lds(
        (const __attribute__((address_space(1))) void*)g,
        (__attribute__((address_space(3))) void*)l, 16, 0, 0);
}

// ---------------- K0: transpose+convert both weights: WT[n][k]=bf16(W[k][n]) --
__global__ __launch_bounds__(256) void k_convT2(const float* __restrict__ W0, const float* __restrict__ W1,
                                                bf16* __restrict__ T0, bf16* __restrict__ T1){
    __shared__ float t[32][33];
    const float* W = blockIdx.z ? W1 : W0;
    bf16* WT = blockIdx.z ? T1 : T0;
    int k0 = blockIdx.y * 32, n0 = blockIdx.x * 32;
    int tx = threadIdx.x & 31, ty = threadIdx.x >> 5;
    for (int i = ty; i < 32; i += 8) t[i][tx] = W[(size_t)(k0 + i) * 1024 + n0 + tx];
    __syncthreads();
    for (int i = ty; i < 32; i += 8)
        WT[(size_t)(n0 + i) * 1024 + k0 + tx] = __float2bfloat16(t[tx][i]);
}

// ---------------- K0b: plain casts ----------------
__global__ void k_cvt_ccw(const float* __restrict__ ccw, bf16* __restrict__ ccwb){
    int i = blockIdx.x * 256 + threadIdx.x;
    ccwb[i] = __float2bfloat16(ccw[i]);
}
__global__ void k_cvt4(const float* __restrict__ src, bf16* __restrict__ dst){
    int i = (blockIdx.x * 256 + threadIdx.x) * 4;
    float4 v = *(const float4*)(src + i);
    dst[i + 0] = __float2bfloat16(v.x);
    dst[i + 1] = __float2bfloat16(v.y);
    dst[i + 2] = __float2bfloat16(v.z);
    dst[i + 3] = __float2bfloat16(v.w);
}

// ---------------- K1: adj_s (bf16, [80][88] padded rows) ----------------
__global__ void k_adj(const float* __restrict__ A, bf16* __restrict__ adjb){
    __shared__ float d[N_];
    int t = threadIdx.x;
    if (t < N_){
        float s = 0.f;
        for (int j = 0; j < N_; j++) s += A[t * N_ + j];
        d[t] = rsqrtf(s);
    }
    __syncthreads();
    for (int idx = t; idx < N_ * N_; idx += 256){
        int i = idx / N_, j = idx - i * N_;
        adjb[i * 88 + j] = __float2bfloat16(d[i] * A[j * N_ + i] * d[j]);
    }
}

// ---------------- K2: h1 = bf16(leaky(adj_s @ x[b])) via MFMA ----------------
// 128 cols per block, 2 waves. grid (B, 8).
__global__ __launch_bounds__(128) void k_prop_static(const float* __restrict__ xsrc,
                                                     const bf16* __restrict__ Ag,
                                                     bf16* __restrict__ H){
    __shared__ bf16 Btl[128 * 88];
    __shared__ bf16 Al [80 * 88];
    int b = blockIdx.x, c0 = blockIdx.y * 128, tid = threadIdx.x;
    int wave = tid >> 6, lane = tid & 63;
    int l15 = lane & 15, hi = lane >> 4;

    #pragma unroll
    for (int k = 0; k < 7; k++){
        int cb = k * 128 + wave * 64;
        if (cb + lane < 880)
            gll16(Ag + (size_t)(cb + lane) * 8, Al + (size_t)cb * 8);
    }
    {
        size_t rowbase = (size_t)b * 81920 + c0 + tid;
        #pragma unroll 8
        for (int m = 0; m < 80; m++)
            Btl[tid * 88 + m] = __float2bfloat16(xsrc[rowbase + (size_t)m * 1024]);
    }
    __syncthreads();

    f32x4 acc[5][4];
    #pragma unroll
    for (int i = 0; i < 5; i++)
        #pragma unroll
        for (int j = 0; j < 4; j++) acc[i][j] = (f32x4){0.f, 0.f, 0.f, 0.f};

    #pragma unroll
    for (int ks = 0; ks < 3; ks++){
        bf16x8 a[5], bv[4];
        if (ks < 2){
            int k0 = ks * 32;
            #pragma unroll
            for (int i = 0; i < 5; i++)
                a[i] = *(const bf16x8*)(Al + (i * 16 + l15) * 88 + k0 + hi * 8);
            #pragma unroll
            for (int j = 0; j < 4; j++)
                bv[j] = *(const bf16x8*)(Btl + (wave * 64 + j * 16 + l15) * 88 + k0 + hi * 8);
        } else {
            int koff = (hi < 2) ? 64 + hi * 8 : 0;
            #pragma unroll
            for (int i = 0; i < 5; i++){
                bf16x8 v = *(const bf16x8*)(Al + (i * 16 + l15) * 88 + koff);
                if (hi >= 2) v = 0;
                a[i] = v;
            }
            #pragma unroll
            for (int j = 0; j < 4; j++){
                bf16x8 v = *(const bf16x8*)(Btl + (wave * 64 + j * 16 + l15) * 88 + koff);
                if (hi >= 2) v = 0;
                bv[j] = v;
            }
        }
        #pragma unroll
        for (int i = 0; i < 5; i++)
            #pragma unroll
            for (int j = 0; j < 4; j++)
                acc[i][j] = __builtin_amdgcn_mfma_f32_16x16x32_bf16(a[i], bv[j], acc[i][j], 0, 0, 0);
    }

    #pragma unroll
    for (int i = 0; i < 5; i++){
        #pragma unroll
        for (int r = 0; r < 4; r++){
            int orow = i * 16 + hi * 4 + r;
            #pragma unroll
            for (int j = 0; j < 4; j++){
                int ocol = c0 + wave * 64 + j * 16 + l15;
                H[(size_t)b * 81920 + (size_t)orow * 1024 + ocol] =
                    __float2bfloat16(leaky(acc[i][j][r]));
            }
        }
    }
}

// ---------------- K3/K13: bf16 MFMA GEMM, A 3-buf / B 2-buf (r9, 69us) -------
template<int EPI>
__global__ __launch_bounds__(256, 4) void k_gemm_mfma(const bf16* __restrict__ Abf,
                                                      const bf16* __restrict__ WT,
                                                      const float* __restrict__ Res,
                                                      void* __restrict__ Outv){
    __shared__ alignas(16) bf16 As[3][128 * 32];
    __shared__ alignas(16) bf16 Bs[2][128 * 32];
    const int K = 1024;
    const int NT = 32;
    int tid = threadIdx.x;
    int wave = tid >> 6, lane = tid & 63;
    int l15 = lane & 15, hi = lane >> 4;

    int bid = blockIdx.x;
    int xcd = bid & 7, idx = bid >> 3;
    int row0 = (xcd * 20 + (idx >> 3)) * 128;
    int col0 = (idx & 7) * 128;

    int sr = tid >> 2;
    int sq = (tid & 3) ^ ((tid >> 3) & 3);
    const bf16* gA = Abf + (size_t)(row0 + sr) * K + sq * 8;
    const bf16* gB = WT  + (size_t)(col0 + sr) * K + sq * 8;

    int wr = (wave >> 1) * 64, wc = (wave & 1) * 64;
    int soff = (hi ^ ((l15 >> 1) & 3)) * 8;

    f32x4 acc[4][4];
    #pragma unroll
    for (int i = 0; i < 4; i++)
        #pragma unroll
        for (int j = 0; j < 4; j++) acc[i][j] = (f32x4){0.f, 0.f, 0.f, 0.f};

    auto STAGE_A = [&](int t){
        bf16* da = &As[t % 3][wave * 512];
        gll16(gA + t * 32, da);
        gll16(gA + (size_t)64 * K + t * 32, da + 2048);
    };
    auto STAGE_B = [&](int t){
        bf16* db = &Bs[t & 1][wave * 512];
        gll16(gB + t * 32, db);
        gll16(gB + (size_t)64 * K + t * 32, db + 2048);
    };

    STAGE_A(0); STAGE_B(0); STAGE_A(1);
    for (int t = 0; t < NT; ++t){
        if (t < NT - 1) asm volatile("s_waitcnt vmcnt(2)" ::: "memory");
        else            asm volatile("s_waitcnt vmcnt(0)" ::: "memory");
        __builtin_amdgcn_s_barrier();
        if (t + 1 < NT) STAGE_B(t + 1);
        if (t + 2 < NT) STAGE_A(t + 2);
        const bf16* pa = &As[t % 3][0] + (wr + l15) * 32 + soff;
        const bf16* pb = &Bs[t & 1][0] + (wc + l15) * 32 + soff;
        bf16x8 a[4], b[4];
        #pragma unroll
        for (int i = 0; i < 4; i++) a[i] = *(const bf16x8*)(pa + i * 512);
        #pragma unroll
        for (int j = 0; j < 4; j++) b[j] = *(const bf16x8*)(pb + j * 512);
        __builtin_amdgcn_s_setprio(1);
        #pragma unroll
        for (int i = 0; i < 4; i++)
            #pragma unroll
            for (int j = 0; j < 4; j++)
                acc[i][j] = __builtin_amdgcn_mfma_f32_16x16x32_bf16(a[i], b[j], acc[i][j], 0, 0, 0);
        __builtin_amdgcn_s_setprio(0);
    }

    int orow = row0 + wr + hi * 4;
    int ocol = col0 + wc + l15;
    #pragma unroll
    for (int i = 0; i < 4; i++){
        #pragma unroll
        for (int r = 0; r < 4; r++){
            int rr = orow + i * 16 + r;
            #pragma unroll
            for (int j = 0; j < 4; j++){
                size_t o = (size_t)rr * 1024 + ocol + j * 16;
                float v = acc[i][j][r];
                if (EPI == 0) ((bf16*)Outv)[o] = __float2bfloat16(v + Res[o]);
                else          ((float*)Outv)[o] = leaky(v);
            }
        }
    }
}

// ---------------- K5: GLB1[b][co] = GLB0b @ cgw^T + cgb, bf16 MFMA -----------
__global__ __launch_bounds__(256) void k_gemm_glb(const bf16* __restrict__ Abf,
                                                  const bf16* __restrict__ Bw,
                                                  const float* __restrict__ bias,
                                                  float* __restrict__ Out){
    __shared__ alignas(16) bf16 As[3][128 * 32];
    __shared__ alignas(16) bf16 Bs[3][128 * 32];
    const int K = 1024;
    const int NT = 32;
    int tid = threadIdx.x;
    int wave = tid >> 6, lane = tid & 63;
    int l15 = lane & 15, hi = lane >> 4;

    int row0 = (blockIdx.x >> 3) * 128;
    int col0 = (blockIdx.x & 7) * 128;

    int sr = tid >> 2;
    int sq = (tid & 3) ^ ((tid >> 3) & 3);
    const bf16* gA = Abf + (size_t)(row0 + sr) * K + sq * 8;
    const bf16* gB = Bw  + (size_t)(col0 + sr) * K + sq * 8;

    int wr = (wave >> 1) * 64, wc = (wave & 1) * 64;
    int soff = (hi ^ ((l15 >> 1) & 3)) * 8;

    f32x4 acc[4][4];
    #pragma unroll
    for (int i = 0; i < 4; i++)
        #pragma unroll
        for (int j = 0; j < 4; j++) acc[i][j] = (f32x4){0.f, 0.f, 0.f, 0.f};

    auto STAGE = [&](int t){
        int buf = t % 3;
        int k0 = t * 32;
        bf16* da = &As[buf][wave * 512];
        bf16* db = &Bs[buf][wave * 512];
        gll16(gA + k0, da);
        gll16(gA + (size_t)64 * K + k0, da + 2048);
        gll16(gB + k0, db);
        gll16(gB + (size_t)64 * K + k0, db + 2048);
    };

    STAGE(0);
    STAGE(1);
    for (int t = 0; t < NT; ++t){
        if (t == NT - 1) asm volatile("s_waitcnt vmcnt(0)" ::: "memory");
        else             asm volatile("s_waitcnt vmcnt(4)" ::: "memory");
        __builtin_amdgcn_s_barrier();
        if (t + 2 < NT) STAGE(t + 2);
        int buf = t % 3;
        const bf16* pa = &As[buf][0] + (wr + l15) * 32 + soff;
        const bf16* pb = &Bs[buf][0] + (wc + l15) * 32 + soff;
        bf16x8 a[4], b[4];
        #pragma unroll
        for (int i = 0; i < 4; i++) a[i] = *(const bf16x8*)(pa + i * 512);
        #pragma unroll
        for (int j = 0; j < 4; j++) b[j] = *(const bf16x8*)(pb + j * 512);
        #pragma unroll
        for (int i = 0; i < 4; i++)
            #pragma unroll
            for (int j = 0; j < 4; j++)
                acc[i][j] = __builtin_amdgcn_mfma_f32_16x16x32_bf16(a[i], b[j], acc[i][j], 0, 0, 0);
    }

    int orow = row0 + wr + hi * 4;
    int ocol = col0 + wc + l15;
    #pragma unroll
    for (int i = 0; i < 4; i++){
        #pragma unroll
        for (int r = 0; r < 4; r++){
            int rr = orow + i * 16 + r;
            #pragma unroll
            for (int j = 0; j < 4; j++){
                int cl = ocol + j * 16;
                Out[(size_t)rr * 1024 + cl] = acc[i][j][r] + bias[cl];
            }
        }
    }
}

// ---------------- K4: glb0b[b,c] = bf16(mean_n x2b[b,n,c]) ----------------
__global__ __launch_bounds__(128) void k_pool(const bf16* __restrict__ X2b, bf16* __restrict__ glb0b){
    int b = blockIdx.x, c8 = threadIdx.x * 8;
    const bf16* p = X2b + (size_t)b * 81920 + c8;
    float s[8] = {0.f,0.f,0.f,0.f,0.f,0.f,0.f,0.f};
    #pragma unroll 8
    for (int nn = 0; nn < N_; nn++){
        union { bf16x8 v; bf16 e[8]; } u;
        u.v = *(const bf16x8*)(p + (size_t)nn * 1024);
        #pragma unroll
        for (int k = 0; k < 8; k++) s[k] += __bfloat162float(u.e[k]);
    }
    #pragma unroll
    for (int k = 0; k < 8; k++)
        glb0b[b * C_ + c8 + k] = __float2bfloat16(s[k] * (1.f / N_));
}

// ---------------- K6: BN stats over batch (high-TLP) ----------------
__global__ __launch_bounds__(256) void k_bnstat(const float* __restrict__ g, float* __restrict__ mu,
                                                float* __restrict__ rstd){
    __shared__ float rs[8][32], rs2[8][32];
    int tid = threadIdx.x;
    int c = blockIdx.x * 32 + (tid & 31);
    int grp = tid >> 5;
    float s = 0.f, s2 = 0.f;
    for (int bb = 0; bb < 32; bb++){
        float v = g[(size_t)(grp * 32 + bb) * 1024 + c];
        s += v; s2 += v * v;
    }
    rs[grp][tid & 31] = s;
    rs2[grp][tid & 31] = s2;
    __syncthreads();
    if (tid < 32){
        float S = 0.f, S2 = 0.f;
        #pragma unroll
        for (int q = 0; q < 8; q++){ S += rs[q][tid]; S2 += rs2[q][tid]; }
        float m = S * (1.f / B_);
        float var = S2 * (1.f / B_) - m * m;
        int cc = blockIdx.x * 32 + tid;
        mu[cc] = m;
        rstd[cc] = rsqrtf(var + 1e-5f);
    }
}

// ---------------- K7: glb2b = bf16(leaky(BN(glb1))) ----------------
__global__ void k_bnapply(const float* __restrict__ g, const float* __restrict__ mu,
                          const float* __restrict__ rstd, const float* __restrict__ gamma,
                          const float* __restrict__ beta, bf16* __restrict__ o){
    int i = blockIdx.x * 256 + threadIdx.x;
    int c = i & (C_ - 1);
    float v = (g[i] - mu[c]) * rstd[c] * gamma[c] + beta[c];
    o[i] = __float2bfloat16(leaky(v));
}

// ---------------- K9: MEGA-FUSED dyn + loss + adj + dynamic propagation -----
// One block per b, 512 threads (8 waves). LDS: S[80][81] f32 (union'd with
// Btl[128][90] bf16 for the prop phase), ADJ[80][90] bf16, small arrays.
// Phase 1 (waves 0-4): S = sigmoid(ccw @ [glb2 ; x2^T] + ccb)  (operand-free)
// Phase 2/3: dinv, loss; Phase 4: ADJ in LDS; Phase 5: H = leaky(ADJ @ x2),
// 8 chunks of 128 cols, wave w owns 16 cols per chunk.
__global__ __launch_bounds__(512) void k_dyn_prop(const bf16* __restrict__ X2b,
                                                  const bf16* __restrict__ ccwb,
                                                  const bf16* __restrict__ glb2b,
                                                  const float* __restrict__ ccb,
                                                  const float* __restrict__ out1,
                                                  bf16* __restrict__ H,
                                                  float* __restrict__ lossp){
    __shared__ char uSb[80 * 81 * 4];       // S f32 [80][81]  /  Btl bf16 [128][90]
    __shared__ bf16 ADJ[80 * 90];
    __shared__ float di_s[80], o1s[80], dd[80];
    float* S = (float*)uSb;
    bf16* Btl = (bf16*)uSb;
    int b = blockIdx.x, tid = threadIdx.x;
    int wave = tid >> 6, lane = tid & 63;
    int l15 = lane & 15, hi = lane >> 4;

    // ---- Phase 1: dyn scores (waves 0-4 only; no barriers inside)
    if (wave < 5){
        const bf16* arow = ccwb + (size_t)(wave * 16 + l15) * 2048 + hi * 8;
        const bf16* gG = glb2b + (size_t)b * 1024 + hi * 8;
        const bf16* gX = X2b + (size_t)b * 81920 + hi * 8;
        f32x4 acc[5];
        #pragma unroll
        for (int j = 0; j < 5; j++) acc[j] = (f32x4){0.f, 0.f, 0.f, 0.f};
        #pragma unroll 8
        for (int k0 = 0; k0 < 1024; k0 += 32){
            bf16x8 a = *(const bf16x8*)(arow + k0);
            bf16x8 g = *(const bf16x8*)(gG + k0);
            #pragma unroll
            for (int j = 0; j < 5; j++)
                acc[j] = __builtin_amdgcn_mfma_f32_16x16x32_bf16(a, g, acc[j], 0, 0, 0);
        }
        #pragma unroll 4
        for (int k0 = 0; k0 < 1024; k0 += 32){
            bf16x8 a = *(const bf16x8*)(arow + 1024 + k0);
            #pragma unroll
            for (int j = 0; j < 5; j++){
                bf16x8 bv = *(const bf16x8*)(gX + (size_t)(j * 16 + l15) * 1024 + k0);
                acc[j] = __builtin_amdgcn_mfma_f32_16x16x32_bf16(a, bv, acc[j], 0, 0, 0);
            }
        }
        #pragma unroll
        for (int r = 0; r < 4; r++){
            int n = wave * 16 + hi * 4 + r;
            float cb = ccb[n];
            #pragma unroll
            for (int j = 0; j < 5; j++)
                S[n * 81 + j * 16 + l15] = sigmoidf_(acc[j][r] + cb);
        }
    }
    __syncthreads();
    // ---- Phase 2: row sums -> dinv; sigmoid(out1)
    if (tid < 80){
        float rsum = 0.f;
        #pragma unroll 8
        for (int m = 0; m < 80; m++) rsum += S[tid * 81 + m];
        di_s[tid] = rsqrtf(rsum);
        o1s[tid] = sigmoidf_(out1[b * 80 + tid]);
    }
    __syncthreads();
    // ---- Phase 3: weighted col sums -> loss parts
    if (tid < 80){
        float cs = 0.f;
        #pragma unroll 8
        for (int n = 0; n < 80; n++) cs += o1s[n] * S[n * 81 + tid];
        float diff = o1s[tid] - cs * (1.f / 80.f);
        dd[tid] = diff * diff;
    }
    __syncthreads();
    // ---- Phase 4: ADJ[n][m] = bf16(di[n]*S[m][n]*di[m]); loss finalize
    for (int idx = tid; idx < 6400; idx += 512){
        int n = idx / 80, m = idx - n * 80;
        ADJ[n * 90 + m] = __float2bfloat16(di_s[n] * S[m * 81 + n] * di_s[m]);
    }
    if (tid == 0){
        float s = 0.f;
        for (int m = 0; m < 80; m++) s += dd[m];
        lossp[b] = sqrtf(s);
    }
    // ---- Phase 5: H = leaky(ADJ @ x2), 8 chunks x 128 cols (Btl reuses S mem)
    for (int c0 = 0; c0 < 1024; c0 += 128){
        __syncthreads();                 // prior chunk reads done / S free
        {
            int cc = tid & 127, g = tid >> 7;          // 4 row-groups of 20
            const bf16* src = X2b + (size_t)b * 81920 + c0 + cc;
            #pragma unroll 5
            for (int m = g * 20; m < g * 20 + 20; m++)
                Btl[cc * 90 + m] = src[(size_t)m * 1024];
        }
        __syncthreads();
        f32x4 pacc[5];
        #pragma unroll
        for (int i = 0; i < 5; i++) pacc[i] = (f32x4){0.f, 0.f, 0.f, 0.f};
        #pragma unroll
        for (int ks = 0; ks < 3; ks++){
            int koff = (ks < 2) ? ks * 32 + hi * 8 : ((hi < 2) ? 64 + hi * 8 : 0);
            bool dead = (ks == 2) && (hi >= 2);
            bf16x8 bv = *(const bf16x8*)(Btl + (wave * 16 + l15) * 90 + koff);
            if (dead) bv = 0;
            #pragma unroll
            for (int i = 0; i < 5; i++){
                bf16x8 a = *(const bf16x8*)(ADJ + (i * 16 + l15) * 90 + koff);
                if (dead) a = 0;
                pacc[i] = __builtin_amdgcn_mfma_f32_16x16x32_bf16(a, bv, pacc[i], 0, 0, 0);
            }
        }
        #pragma unroll
        for (int i = 0; i < 5; i++){
            #pragma unroll
            for (int r = 0; r < 4; r++){
                int n = i * 16 + hi * 4 + r;
                int col = c0 + wave * 16 + l15;
                H[(size_t)b * 81920 + (size_t)n * 1024 + col] =
                    __float2bfloat16(leaky(pacc[i][r]));
            }
        }
    }
}

// ---------------- K11: loss = sum(lossp) ----------------
__global__ void k_lsum(const float* __restrict__ lossp, float* __restrict__ out_loss){
    float v = lossp[threadIdx.x];
    for (int off = 32; off; off >>= 1) v += __shfl_down(v, off);
    __shared__ float wsum[4];
    int lane = threadIdx.x & 63, w = threadIdx.x >> 6;
    if (lane == 0) wsum[w] = v;
    __syncthreads();
    if (threadIdx.x == 0) out_loss[0] = wsum[0] + wsum[1] + wsum[2] + wsum[3];
}

extern "C" void kernel_launch(void* const* d_in, const int* in_sizes, int n_in,
                              void* d_out, int out_size, void* d_ws, size_t ws_size,
                              hipStream_t stream) {
    const float* x     = (const float*)d_in[0];
    const float* out1  = (const float*)d_in[1];
    const float* A     = (const float*)d_in[2];
    const float* sw    = (const float*)d_in[3];
    const float* cgw   = (const float*)d_in[4];
    const float* cgb   = (const float*)d_in[5];
    const float* gamma = (const float*)d_in[6];
    const float* beta  = (const float*)d_in[7];
    const float* ccw   = (const float*)d_in[8];
    const float* ccb   = (const float*)d_in[9];
    const float* dw    = (const float*)d_in[10];
    float* out = (float*)d_out;

    const size_t XN = (size_t)B_ * N_ * C_;   // 20,971,520
    char* p = (char*)d_ws;
    bf16*  Hbf  = (bf16*)p;   p += XN * 2;               // 42 MB
    bf16*  X2b  = (bf16*)p;   p += XN * 2;               // 42 MB
    bf16*  SWT  = (bf16*)p;   p += (size_t)C_ * C_ * 2;  // 2 MB
    bf16*  DWT  = (bf16*)p;   p += (size_t)C_ * CO_ * 2; // 2 MB
    bf16*  CCWB = (bf16*)p;   p += (size_t)N_ * 2048 * 2;
    bf16*  CGWB = (bf16*)p;   p += (size_t)C_ * C_ * 2;  // 2 MB
    bf16*  ADJS = (bf16*)p;   p += (size_t)80 * 88 * 2;
    bf16*  GLB0 = (bf16*)p;   p += (size_t)B_ * C_ * 2;
    float* GLB1 = (float*)p;  p += (size_t)B_ * C_ * 4;
    bf16*  GLB2 = (bf16*)p;   p += (size_t)B_ * C_ * 2;
    float* MU   = (float*)p;  p += C_ * 4;
    float* RSTD = (float*)p;  p += C_ * 4;
    float* LOSSP= (float*)p;  p += B_ * 4;

    k_convT2<<<dim3(32, 32, 2), 256, 0, stream>>>(sw, dw, SWT, DWT);
    k_cvt_ccw<<<(N_ * 2048) / 256, 256, 0, stream>>>(ccw, CCWB);
    k_cvt4<<<(C_ * C_) / 1024, 256, 0, stream>>>(cgw, CGWB);
    k_adj<<<1, 256, 0, stream>>>(A, ADJS);
    k_prop_static<<<dim3(B_, 8), 128, 0, stream>>>(x, ADJS, Hbf);
    k_gemm_mfma<0><<<1280, 256, 0, stream>>>(Hbf, SWT, x, X2b);
    k_pool<<<B_, 128, 0, stream>>>(X2b, GLB0);
    k_gemm_glb<<<16, 256, 0, stream>>>(GLB0, CGWB, cgb, GLB1);
    k_bnstat<<<32, 256, 0, stream>>>(GLB1, MU, RSTD);
    k_bnapply<<<(B_ * C_) / 256, 256, 0, stream>>>(GLB1, MU, RSTD, gamma, beta, GLB2);
    k_dyn_prop<<<B_, 512, 0, stream>>>(X2b, CCWB, GLB2, ccb, out1, Hbf, LOSSP);
    k_lsum<<<1, 256, 0, stream>>>(LOSSP, out + (size_t)B_ * N_ * CO_);
    k_gemm_mfma<1><<<1280, 256, 0, stream>>>(Hbf, DWT, nullptr, out);
}